// Round 4
// baseline (471.464 us; speedup 1.0000x reference)
//
#include <hip/hip_runtime.h>

#define N_NODES 50000
#define N_EDGES 500000
#define D_NODE 64
#define D_EDGE 32
#define MSG_DIM 160
#define HID_DIM 224
#define ALPHA 0.01f

#define FNB 32          // nodes per fused block
#define A_STRIDE 168    // 160 + 8 pad (shorts) -> conflict-free b128 frag reads
#define MACC_STRIDE 164 // 160 + 4 pad (floats): breaks %32==0 bank aliasing, keeps 16B align
#define NPART 196       // ceil(50000/256) scan partials

typedef unsigned short u16;
typedef short short8 __attribute__((ext_vector_type(8)));
typedef float float4v __attribute__((ext_vector_type(4)));

static __device__ __forceinline__ u16 f2bf(float f) {
    unsigned int u = __float_as_uint(f);
    u += 0x7fffu + ((u >> 16) & 1u);   // round-to-nearest-even
    return (u16)(u >> 16);
}

// one kernel converts h_n, W_msg, W_hid to bf16 (saves 2 launches)
__global__ __launch_bounds__(256) void cvt_all(const float* __restrict__ h_n,
                                               const float* __restrict__ W_msg,
                                               const float* __restrict__ W_hid,
                                               u16* __restrict__ hn_bf,
                                               u16* __restrict__ Wm_bf,
                                               u16* __restrict__ Wh_bf) {
    int i = blockIdx.x * 256 + threadIdx.x;
    const float* in; u16* outp; int j;
    if (i < 800000)      { in = h_n;   outp = hn_bf; j = i; }
    else if (i < 806400) { in = W_msg; outp = Wm_bf; j = i - 800000; }
    else if (i < 818944) { in = W_hid; outp = Wh_bf; j = i - 806400; }
    else return;
    float4 v = reinterpret_cast<const float4*>(in)[j];
    ushort4 o;
    o.x = f2bf(v.x); o.y = f2bf(v.y); o.z = f2bf(v.z); o.w = f2bf(v.w);
    reinterpret_cast<ushort4*>(outp)[j] = o;
}

// ---------------- counting sort by dst (hist -> hierarchical scan -> scatter) ----
__global__ __launch_bounds__(256) void hist_kernel(const int* __restrict__ dst,
                                                   int* __restrict__ cnt) {
    int e = blockIdx.x * 256 + threadIdx.x;
    if (e < N_EDGES) atomicAdd(&cnt[dst[e]], 1);
}

__global__ __launch_bounds__(256) void partial_kernel(const int* __restrict__ cnt,
                                                      int* __restrict__ partial) {
    __shared__ int sd[256];
    const int tid = threadIdx.x;
    int i = blockIdx.x * 256 + tid;
    sd[tid] = (i < N_NODES) ? cnt[i] : 0;
    __syncthreads();
    for (int off = 128; off > 0; off >>= 1) {
        if (tid < off) sd[tid] += sd[tid + off];
        __syncthreads();
    }
    if (tid == 0) partial[blockIdx.x] = sd[0];
}

__global__ __launch_bounds__(256) void offs_kernel(int* __restrict__ partial) {
    __shared__ int sd[256];
    const int t = threadIdx.x;
    int v = (t < NPART) ? partial[t] : 0;
    sd[t] = v;
    __syncthreads();
    for (int off = 1; off < 256; off <<= 1) {
        int u = (t >= off) ? sd[t - off] : 0;
        __syncthreads();
        sd[t] += u;
        __syncthreads();
    }
    if (t < NPART) partial[t] = sd[t] - v;   // exclusive
}

__global__ __launch_bounds__(256) void cursor_kernel(const int* __restrict__ cnt,
                                                     const int* __restrict__ partial,
                                                     int* __restrict__ cursor,
                                                     int* __restrict__ row_ptr) {
    __shared__ int sd[256];
    const int tid = threadIdx.x;
    int i = blockIdx.x * 256 + tid;
    int v = (i < N_NODES) ? cnt[i] : 0;
    sd[tid] = v;
    __syncthreads();
    for (int off = 1; off < 256; off <<= 1) {
        int u = (tid >= off) ? sd[tid - off] : 0;
        __syncthreads();
        sd[tid] += u;
        __syncthreads();
    }
    if (i < N_NODES) {
        int start = partial[blockIdx.x] + sd[tid] - v;   // exclusive prefix
        cursor[i] = start;
        row_ptr[i] = start;          // pristine copy (scatter destroys cursor)
    }
}

__global__ __launch_bounds__(256) void scatter_kernel(const int* __restrict__ src,
                                                      const int* __restrict__ dst,
                                                      int* __restrict__ cursor,
                                                      int* __restrict__ eid_s,
                                                      int* __restrict__ src_s,
                                                      int* __restrict__ dst_s) {
    int e = blockIdx.x * 256 + threadIdx.x;
    if (e < N_EDGES) {
        int d = dst[e];
        int p = atomicAdd(&cursor[d], 1);
        eid_s[p] = e;
        src_s[p] = src[e];
        dst_s[p] = d;
    }
}

// ---------------- fused edge-message + reduce + node-update kernel ----------------
// Block b owns nodes [32b, 32b+32) = sorted edges [row_ptr[n0], p_end).
// Phase 1: 64-edge tiles -> transposed MFMA C[f][e] -> segmented shuffle scan
//          -> ds_add_f32 into LDS m_acc (no global atomics, no m_sum).
// Phase 2: update GEMM from m_acc(+h_n) with W_hid, write out directly.
__global__ __launch_bounds__(256) void fused_kernel(
    const u16* __restrict__ hn_bf, const float* __restrict__ h_e,
    const int* __restrict__ src_s, const int* __restrict__ dst_s,
    const int* __restrict__ eid_s, const int* __restrict__ row_ptr,
    const u16* __restrict__ Wm_bf, const float* __restrict__ b_msg,
    const u16* __restrict__ Wh_bf, const float* __restrict__ b_hid,
    float* __restrict__ out)
{
    __shared__ alignas(16) u16 X_lds[64 * A_STRIDE];        // 21504 B
    __shared__ alignas(16) float m_acc[FNB * MACC_STRIDE];  // 20992 B
    __shared__ int dst_lds[64];                             //   256 B

    const int tid = threadIdx.x;
    const int n0 = blockIdx.x * FNB;
    const int p_begin = row_ptr[n0];
    const int p_end = (n0 + FNB < N_NODES) ? row_ptr[n0 + FNB] : N_EDGES;

    for (int i = tid; i < FNB * MACC_STRIDE; i += 256) m_acc[i] = 0.f;

    const int wave = tid >> 6, lane = tid & 63;
    const int qd = lane >> 4, l15 = lane & 15;

    // ---------------- phase 1: edge tiles ----------------
    for (int p0 = p_begin; p0 < p_end; p0 += 64) {
        {   // stage 64 sorted edges x 160 bf16 (4 threads per edge)
            const int e_loc = tid >> 2, j = tid & 3;
            int pp = p0 + e_loc; if (pp > p_end - 1) pp = p_end - 1;
            const int s = src_s[pp], d = dst_s[pp], eo = eid_s[pp];
            if (j == 0) dst_lds[e_loc] = d;
            const uint4* srow = reinterpret_cast<const uint4*>(hn_bf + (size_t)s * D_NODE);
            const uint4* drow = reinterpret_cast<const uint4*>(hn_bf + (size_t)d * D_NODE);
            uint4* Arow = reinterpret_cast<uint4*>(&X_lds[e_loc * A_STRIDE]);
            Arow[j * 2]     = srow[j * 2];        // bf16 [0,64): h_n[src]
            Arow[j * 2 + 1] = srow[j * 2 + 1];
            Arow[8 + j * 2]     = drow[j * 2];    // bf16 [64,128): h_n[dst]
            Arow[8 + j * 2 + 1] = drow[j * 2 + 1];
            const float4* he = reinterpret_cast<const float4*>(h_e + (size_t)eo * D_EDGE);
            float4 p = he[j * 2], q = he[j * 2 + 1];
            ushort4 lo, hi;
            lo.x = f2bf(p.x); lo.y = f2bf(p.y); lo.z = f2bf(p.z); lo.w = f2bf(p.w);
            hi.x = f2bf(q.x); hi.y = f2bf(q.y); hi.z = f2bf(q.z); hi.w = f2bf(q.w);
            ushort4* Aus = reinterpret_cast<ushort4*>(Arow);
            Aus[32 + j * 2]     = lo;             // bf16 [128,160): h_e
            Aus[32 + j * 2 + 1] = hi;
        }
        __syncthreads();   // staging + (first iter) m_acc zero-init visible

        short8 x_frag[5];
#pragma unroll
        for (int ks = 0; ks < 5; ++ks)
            x_frag[ks] = *reinterpret_cast<const short8*>(
                &X_lds[(wave * 16 + l15) * A_STRIDE + ks * 32 + qd * 8]);

        const int my_dst = dst_lds[wave * 16 + l15];
        const int rel = my_dst - n0;              // in [0, FNB) by sort construction
        const bool ok = (p0 + wave * 16 + l15) < p_end;

        const int nxt = __shfl(my_dst, (lane + 1) & 63);
        const bool seg_last = (l15 == 15) || (nxt != my_dst);
        bool pr[4];
#pragma unroll
        for (int s = 1, i = 0; s < 16; s <<= 1, ++i) {
            int pd = __shfl(my_dst, (lane - s) & 63);
            pr[i] = (l15 >= s) && (pd == my_dst);
        }

        for (int c = 0; c < 10; ++c) {            // 10 chunks of 16 features
            const int fbase = c * 16;
            float4v acc = {0.f, 0.f, 0.f, 0.f};
#pragma unroll
            for (int ks = 0; ks < 5; ++ks) {
                short8 w = *reinterpret_cast<const short8*>(
                    Wm_bf + (size_t)(fbase + l15) * MSG_DIM + ks * 32 + qd * 8);
                acc = __builtin_amdgcn_mfma_f32_16x16x32_bf16(w, x_frag[ks], acc, 0, 0, 0);
            }
            const float4 bias = *reinterpret_cast<const float4*>(b_msg + fbase + qd * 4);
            float v0 = acc[0] + bias.x, v1 = acc[1] + bias.y,
                  v2 = acc[2] + bias.z, v3 = acc[3] + bias.w;
            v0 = v0 > 0.f ? v0 : ALPHA * v0;  v1 = v1 > 0.f ? v1 : ALPHA * v1;
            v2 = v2 > 0.f ? v2 : ALPHA * v2;  v3 = v3 > 0.f ? v3 : ALPHA * v3;
            if (!ok) { v0 = v1 = v2 = v3 = 0.f; }

            // segmented inclusive scan along l15 (runs of equal dst)
#pragma unroll
            for (int s = 1, i = 0; s < 16; s <<= 1, ++i) {
                const int sl = (lane - s) & 63;
                float t0 = __shfl(v0, sl), t1 = __shfl(v1, sl),
                      t2 = __shfl(v2, sl), t3 = __shfl(v3, sl);
                if (pr[i]) { v0 += t0; v1 += t1; v2 += t2; v3 += t3; }
            }
            if (seg_last) {
                float* row = &m_acc[rel * MACC_STRIDE + fbase + qd * 4];
                atomicAdd(row + 0, v0);           // ds_add_f32: block-local, cheap
                atomicAdd(row + 1, v1);
                atomicAdd(row + 2, v2);
                atomicAdd(row + 3, v3);
            }
        }
        __syncthreads();   // ds_adds + frag reads done before next tile restages
    }
    __syncthreads();       // covers the zero-trip case (m_acc zeros visible)

    // ---------------- phase 2: node update ----------------
    // wave w: node-half nh = w&1 (16 nodes), feature-chunks cbase..cbase+6
    const int nh = wave & 1;
    const int cbase = (wave >> 1) * 7;
    const int node = n0 + nh * 16 + l15;                 // this lane's B-frag node
    const int nclamp = (node < N_NODES) ? node : N_NODES - 1;

    short8 b_frag[7];
#pragma unroll
    for (int ks = 0; ks < 5; ++ks) {                     // k in [0,160): m_acc
        const float* srcp = &m_acc[(nh * 16 + l15) * MACC_STRIDE + ks * 32 + qd * 8];
        float4 f0 = *reinterpret_cast<const float4*>(srcp);
        float4 f1 = *reinterpret_cast<const float4*>(srcp + 4);
        short8 b;
        b[0] = (short)f2bf(f0.x); b[1] = (short)f2bf(f0.y);
        b[2] = (short)f2bf(f0.z); b[3] = (short)f2bf(f0.w);
        b[4] = (short)f2bf(f1.x); b[5] = (short)f2bf(f1.y);
        b[6] = (short)f2bf(f1.z); b[7] = (short)f2bf(f1.w);
        b_frag[ks] = b;
    }
#pragma unroll
    for (int ks = 5; ks < 7; ++ks)                       // k in [160,224): h_n (bf16)
        b_frag[ks] = *reinterpret_cast<const short8*>(
            hn_bf + (size_t)nclamp * D_NODE + (ks - 5) * 32 + qd * 8);

    for (int ci = 0; ci < 7; ++ci) {
        const int c = cbase + ci;
        const int f = c * 16 + l15;                      // A-frag feature row
        float4v acc = {0.f, 0.f, 0.f, 0.f};
#pragma unroll
        for (int ks = 0; ks < 7; ++ks) {
            short8 a = *reinterpret_cast<const short8*>(
                Wh_bf + (size_t)f * HID_DIM + ks * 32 + qd * 8);
            acc = __builtin_amdgcn_mfma_f32_16x16x32_bf16(a, b_frag[ks], acc, 0, 0, 0);
        }
        // C layout: col=l15 -> node, row=qd*4+r -> feature c*16+qd*4+r
        const float4 bias = *reinterpret_cast<const float4*>(b_hid + c * 16 + qd * 4);
        float v0 = acc[0] + bias.x, v1 = acc[1] + bias.y,
              v2 = acc[2] + bias.z, v3 = acc[3] + bias.w;
        v0 = v0 > 0.f ? v0 : ALPHA * v0;  v1 = v1 > 0.f ? v1 : ALPHA * v1;
        v2 = v2 > 0.f ? v2 : ALPHA * v2;  v3 = v3 > 0.f ? v3 : ALPHA * v3;
        if (node < N_NODES) {
            float4 o; o.x = v0; o.y = v1; o.z = v2; o.w = v3;
            *reinterpret_cast<float4*>(&out[(size_t)node * HID_DIM + c * 16 + qd * 4]) = o;
        }
    }
}

extern "C" void kernel_launch(void* const* d_in, const int* in_sizes, int n_in,
                              void* d_out, int out_size, void* d_ws, size_t ws_size,
                              hipStream_t stream)
{
    const float* h_n   = (const float*)d_in[0];
    const float* h_e   = (const float*)d_in[1];
    const int*   src   = (const int*)d_in[2];
    const int*   dst   = (const int*)d_in[3];
    const float* W_msg = (const float*)d_in[4];
    const float* b_msg = (const float*)d_in[5];
    const float* W_hid = (const float*)d_in[6];
    const float* b_hid = (const float*)d_in[7];
    float* out = (float*)d_out;

    char* ws = (char*)d_ws;
    u16* hn_bf   = (u16*)(ws + 0);                   //  6,400,000 B
    u16* Wm_bf   = (u16*)(ws + 6400000);             //     51,200 B
    u16* Wh_bf   = (u16*)(ws + 6451200);             //    100,352 B
    int* cnt     = (int*)(ws + 6551552);             //    200,000 B
    int* cursor  = (int*)(ws + 6751552);             //    200,000 B
    int* row_ptr = (int*)(ws + 6951552);             //    200,000 B
    int* eid_s   = (int*)(ws + 7151552);             //  2,000,000 B
    int* src_s   = (int*)(ws + 9151552);             //  2,000,000 B
    int* dst_s   = (int*)(ws + 11151552);            //  2,000,000 B
    int* partial = (int*)(ws + 13151552);            //        784 B  (~13.2 MB)

    hipMemsetAsync(cnt, 0, (size_t)N_NODES * sizeof(int), stream);
    cvt_all<<<3200, 256, 0, stream>>>(h_n, W_msg, W_hid, hn_bf, Wm_bf, Wh_bf);
    hist_kernel<<<(N_EDGES + 255) / 256, 256, 0, stream>>>(dst, cnt);
    partial_kernel<<<NPART, 256, 0, stream>>>(cnt, partial);
    offs_kernel<<<1, 256, 0, stream>>>(partial);
    cursor_kernel<<<NPART, 256, 0, stream>>>(cnt, partial, cursor, row_ptr);
    scatter_kernel<<<(N_EDGES + 255) / 256, 256, 0, stream>>>(src, dst, cursor, eid_s, src_s, dst_s);
    fused_kernel<<<(N_NODES + FNB - 1) / FNB, 256, 0, stream>>>(
        hn_bf, h_e, src_s, dst_s, eid_s, row_ptr, Wm_bf, b_msg, Wh_bf, b_hid, out);
}